// Round 4
// baseline (571.335 us; speedup 1.0000x reference)
//
#include <hip/hip_runtime.h>

// Perona-Malik diffusion, 500 iters = 50 launches x 10 LDS-fused steps.
// Round-8 change vs round 7: 4x2 units -> 4x4 units (286 threads, 5 waves).
// Only a unit's boundary is consumed by neighbors: per iter each thread does
// 4 b128 reads (up row, dn row, left nbr's right col, right nbr's left col
// via dense per-unit column arrays) + 4 b128 writes (top/bot row, own
// left/right col) = 6 DS-cyc/cell vs 9.5 before (-37% DS issue). Row buffer
// compacted to 2 rows/band (+guards). Column arrays are 16B/unit stride ->
// uniform 8 words/bank. Same per-cell formula text, same coefficient and
// neighbor VALUES -> bit-identical. halo_y=10 not /4: interior masking is
// per-row in the epilogue only.

#define HH 512
#define WW 512
#define NB 2
static constexpr float LAM   = 0.24f;
static constexpr float KCOND = 0.03f;
static constexpr float DEPS_ = 0.1f;
static constexpr int IMG      = HH * WW;
static constexpr int N_DEPTH  = NB * IMG;
static constexpr int CV_PER_B = (HH - 1) * WW;
static constexpr int CH_PER_B = HH * (WW - 1);
static constexpr int N_CV     = NB * CV_PER_B;
static constexpr int N_CH     = NB * CH_PER_B;

static constexpr int T_FUSE = 10, NSS = 50;       // 50 x 10 = 500
static constexpr int TILE_W = 64, TILE_H = 32;
static constexpr int HALO_X = 12, HALO_Y = 10;
static constexpr int RW = TILE_W + 2 * HALO_X;    // 88
static constexpr int RH = TILE_H + 2 * HALO_Y;    // 52
static constexpr int NQ_ROW = RW / 4;             // 22 (also used by fallback)
static constexpr int NQUAD  = NQ_ROW * RH;        // 1144 (fallback)
static constexpr int SSZ    = (RH + 2) * RW;      // fallback layout (4752)

// ---- fast path: 4x4 units, one per thread ----
static constexpr int NU_ROW = RW / 4;              // 22 units per band
static constexpr int NBAND  = RH / 4;              // 13 bands
static constexpr int NUNIT  = NU_ROW * NBAND;      // 286
static constexpr int NTF    = 320;                 // 5 waves

// fast-path LDS layout (floats), per ping-pong buffer:
//   rows : (2*NBAND+2) x S_LDS   only top/bot row of each band + guards
//   trash: inactive-lane writes (distinct 16-float slots)
//   lcol : per-unit left-column  float4 entries (+1 shifted, sentinels 0)
//   rcol : per-unit right-column float4 entries (+1 shifted, sentinels 0)
static constexpr int S_LDS     = 92;
static constexpr int RROWS     = 2 * NBAND + 2;          // 28
static constexpr int ROWS_SZ   = RROWS * S_LDS;          // 2576
static constexpr int TRASH_OFF = ROWS_SZ;                // 2576
static constexpr int TRASH_SZ  = 576;                    // 34*16 rounded up
static constexpr int ECNT      = NUNIT + 2;              // 288
static constexpr int LCOL_OFF  = TRASH_OFF + TRASH_SZ;   // 3152
static constexpr int RCOL_OFF  = LCOL_OFF + ECNT * 4;    // 4304
static constexpr int BUF_SZ    = RCOL_OFF + ECNT * 4;    // 5456 (43.6KB x2)

// coefficient planes (per block): CV rows 0..RH (edge above region row r),
// CH row width padded to 96 so the 5-edge read is aligned f4 + scalar.
static constexpr int CVW = RW;                     // 88
static constexpr int CV_SZ = (RH + 1) * CVW;       // 4664
static constexpr int CHW = RW + 8;                 // 96
static constexpr int CH_SZ = RH * CHW;             // 4992
static constexpr int BLOB_BLK = CV_SZ + CH_SZ;     // 9656 floats/block

// fallback path (round-2 verified): 256 threads, 5 quads/thread
static constexpr int QPT_F = 5;

// ---- monotone float<->uint key for atomic min ----
__device__ __forceinline__ unsigned fkey(float f) {
    unsigned u = __float_as_uint(f);
    return (u & 0x80000000u) ? ~u : (u | 0x80000000u);
}
__device__ __forceinline__ float kinv(unsigned k) {
    return __uint_as_float((k & 0x80000000u) ? (k & 0x7fffffffu) : ~k);
}

__global__ void init_key_kernel(unsigned* key) { *key = 0xFFFFFFFFu; }

__global__ void min_kernel(const float* __restrict__ x, unsigned* key) {
    float m = 3.4e38f;
    for (int idx = blockIdx.x * blockDim.x + threadIdx.x; idx < N_DEPTH;
         idx += gridDim.x * blockDim.x)
        m = fminf(m, x[idx]);
    for (int off = 32; off > 0; off >>= 1) m = fminf(m, __shfl_down(m, off, 64));
    __shared__ float sm[4];
    int lane = threadIdx.x & 63, wv = threadIdx.x >> 6;
    if (lane == 0) sm[wv] = m;
    __syncthreads();
    if (threadIdx.x == 0) {
        float mm = fminf(fminf(sm[0], sm[1]), fminf(sm[2], sm[3]));
        atomicMin(key, fkey(mm));
    }
}

__global__ void coeff_kernel(const float* __restrict__ g, float* __restrict__ cv,
                             float* __restrict__ chh) {
    int idx = blockIdx.x * blockDim.x + threadIdx.x;
    constexpr float kk = KCOND * KCOND;
    if (idx < N_CV) {
        int b = idx / CV_PER_B;
        int r = idx - b * CV_PER_B;
        int i = r >> 9, j = r & (WW - 1);
        const float* gb = g + b * 3 * IMG + i * WW + j;
        float s = 0.f;
#pragma unroll
        for (int c = 0; c < 3; ++c) s += fabsf(gb[c * IMG + WW] - gb[c * IMG]);
        float m = s / 3.0f;
        cv[idx] = 1.0f / (1.0f + (m * m) / kk);
    } else if (idx < N_CV + N_CH) {
        int t = idx - N_CV;
        int b = t / CH_PER_B;
        int r = t - b * CH_PER_B;
        int i = r / (WW - 1);
        int j = r - i * (WW - 1);
        const float* gb = g + b * 3 * IMG + i * WW + j;
        float s = 0.f;
#pragma unroll
        for (int c = 0; c < 3; ++c) s += fabsf(gb[c * IMG + 1] - gb[c * IMG]);
        float m = s / 3.0f;
        chh[t] = 1.0f / (1.0f + (m * m) / kk);
    }
}

// One-time: bake predicated L*cv / L*ch into dense per-block planes.
// CV[rr][x] = coeff of vertical edge ABOVE region row rr (0 where invalid).
// CH[rr][xe] = coeff of horizontal edge whose RIGHT pixel is region col xe.
__global__ __launch_bounds__(256) void prep_planes(const float* __restrict__ cv_g,
                                                   const float* __restrict__ ch_g,
                                                   float* __restrict__ blob) {
    const int blk = blockIdx.x;
    const int b   = blk >> 7, t = blk & 127;
    const int y0  = (t >> 3) * TILE_H;
    const int x0  = (t & 7) * TILE_W;
    const float* cvb = cv_g + b * CV_PER_B;
    const float* chb = ch_g + b * CH_PER_B;
    float* pv = blob + blk * BLOB_BLK;
    float* ph = pv + CV_SZ;
    for (int i = threadIdx.x; i < CV_SZ; i += 256) {
        int rr = i / CVW, x = i - rr * CVW;
        int gy = y0 - HALO_Y + rr, gx = x0 - HALO_X + x;
        bool ok = (rr >= 1) && (rr <= RH - 1) && (gy >= 1) && (gy <= HH - 1) &&
                  (gx >= 0) && (gx < WW);
        pv[i] = ok ? LAM * cvb[(gy - 1) * WW + gx] : 0.f;
    }
    for (int i = threadIdx.x; i < CH_SZ; i += 256) {
        int rr = i / CHW, xe = i - rr * CHW;
        int gy = y0 - HALO_Y + rr, gxe = x0 - HALO_X + xe;
        bool ok = (xe >= 1) && (xe <= RW - 1) && (gy >= 0) && (gy < HH) &&
                  (gxe >= 1) && (gxe < WW);
        ph[i] = ok ? LAM * chb[gy * (WW - 1) + (gxe - 1)] : 0.f;
    }
}

template <bool ADD_SHIFT, bool SUB_SHIFT>
__global__ __launch_bounds__(NTF, 1) void step_fast(
    const float* __restrict__ src, float* __restrict__ dst,
    const float* __restrict__ blob, const unsigned* __restrict__ key) {
    __shared__ float sb[2][BUF_SZ];
    const int blk = blockIdx.x;
    const int b   = blk >> 7, t = blk & 127;
    const int y0  = (t >> 3) * TILE_H;
    const int x0  = (t & 7) * TILE_W;
    const float* srcb = src + b * IMG;
    const float* pv   = blob + blk * BLOB_BLK;
    const float* ph   = pv + CV_SZ;

    float shift = 0.f;
    if (ADD_SHIFT || SUB_SHIFT) shift = (kinv(*key) <= DEPS_) ? DEPS_ : 0.f;
    const int tid = threadIdx.x;

    // ---- unit geometry: 4 wide x 4 tall ----
    const bool act  = tid < NUNIT;
    const int  uc   = act ? tid : 0;
    const int  band = uc / NU_ROW;
    const int  px   = uc - band * NU_ROW;
    const int  x    = px * 4;
    const int  r0   = band * 4;

    // read offsets (always from uc geometry -> valid, finite locations)
    const int ro_t   = (2 * band + 1) * S_LDS + x;   // my top row slot
    const int up_off = ro_t - S_LDS;                 // band-1's bottom (or guard)
    const int dn_off = ro_t + 2 * S_LDS;             // band+1's top (or guard)
    const int e_lf   = RCOL_OFF + uc * 4;            // left nbr's right col
    const int e_rt   = LCOL_OFF + (uc + 2) * 4;      // right nbr's left col
    // write offsets (trash-redirected for inactive lanes)
    int w_t  = ro_t;
    int w_b  = ro_t + S_LDS;
    int e_wl = LCOL_OFF + (tid + 1) * 4;
    int e_wr = RCOL_OFF + (tid + 1) * 4;
    if (!act) {
        int ts = TRASH_OFF + (tid - NUNIT) * 16;
        w_t = ts; w_b = ts + 4; e_wl = ts + 8; e_wr = ts + 12;
    }

    const int gx    = x0 - HALO_X + x;
    const bool gx_in = (gx >= 0) && (gx <= WW - 4);
    const bool x_int = (x >= HALO_X) && (x < HALO_X + TILE_W);
    int  goffr[4];
    bool inr[4], isr[4];
#pragma unroll
    for (int i = 0; i < 4; ++i) {
        int gy   = y0 - HALO_Y + r0 + i;
        inr[i]   = act && gx_in && (gy >= 0) && (gy < HH);
        goffr[i] = inr[i] ? (gy * WW + gx) : 0;
        int rr   = r0 + i;
        isr[i]   = act && x_int && (rr >= HALO_Y) && (rr < HALO_Y + TILE_H);
    }

    // ---- coefficients (baked, predicated; zero-mask inactive lanes) ----
    const float am = act ? 1.f : 0.f;
    float cvv[5][4], hh[4][5];
#pragma unroll
    for (int i = 0; i < 5; ++i) {
        float4 a = *reinterpret_cast<const float4*>(&pv[(r0 + i) * CVW + x]);
        cvv[i][0] = a.x * am; cvv[i][1] = a.y * am;
        cvv[i][2] = a.z * am; cvv[i][3] = a.w * am;
    }
#pragma unroll
    for (int i = 0; i < 4; ++i) {
        float4 u  = *reinterpret_cast<const float4*>(&ph[(r0 + i) * CHW + x]);
        float  u4 = ph[(r0 + i) * CHW + x + 4];
        hh[i][0] = u.x * am; hh[i][1] = u.y * am; hh[i][2] = u.z * am;
        hh[i][3] = u.w * am; hh[i][4] = u4 * am;
    }

    // ---- initial state ----
    float vv[4][4];
#pragma unroll
    for (int i = 0; i < 4; ++i) {
        float4 tv = {0.f, 0.f, 0.f, 0.f};
        if (inr[i]) tv = *reinterpret_cast<const float4*>(srcb + goffr[i]);
        if (ADD_SHIFT && inr[i]) {
            tv.x += shift; tv.y += shift; tv.z += shift; tv.w += shift;
        }
        vv[i][0] = tv.x; vv[i][1] = tv.y; vv[i][2] = tv.z; vv[i][3] = tv.w;
    }

    // guard rows (0 and RROWS-1) zeroed in both buffers
    for (int i = tid; i < S_LDS; i += NTF) {
        sb[0][i] = 0.f; sb[0][(RROWS - 1) * S_LDS + i] = 0.f;
        sb[1][i] = 0.f; sb[1][(RROWS - 1) * S_LDS + i] = 0.f;
    }
    if (tid == 0) {
        float4 z{0.f, 0.f, 0.f, 0.f};
        *reinterpret_cast<float4*>(&sb[0][LCOL_OFF]) = z;
        *reinterpret_cast<float4*>(&sb[1][LCOL_OFF]) = z;
        *reinterpret_cast<float4*>(&sb[0][LCOL_OFF + (ECNT - 1) * 4]) = z;
        *reinterpret_cast<float4*>(&sb[1][LCOL_OFF + (ECNT - 1) * 4]) = z;
        *reinterpret_cast<float4*>(&sb[0][RCOL_OFF]) = z;
        *reinterpret_cast<float4*>(&sb[1][RCOL_OFF]) = z;
        *reinterpret_cast<float4*>(&sb[0][RCOL_OFF + (ECNT - 1) * 4]) = z;
        *reinterpret_cast<float4*>(&sb[1][RCOL_OFF + (ECNT - 1) * 4]) = z;
    }
    *reinterpret_cast<float4*>(&sb[0][w_t])  = float4{vv[0][0], vv[0][1], vv[0][2], vv[0][3]};
    *reinterpret_cast<float4*>(&sb[0][w_b])  = float4{vv[3][0], vv[3][1], vv[3][2], vv[3][3]};
    *reinterpret_cast<float4*>(&sb[0][e_wl]) = float4{vv[0][0], vv[1][0], vv[2][0], vv[3][0]};
    *reinterpret_cast<float4*>(&sb[0][e_wr]) = float4{vv[0][3], vv[1][3], vv[2][3], vv[3][3]};
    __syncthreads();

    int cur = 0;
    for (int it = 0; it < T_FUSE; ++it) {
        const float* s = sb[cur];
        float4 up4 = *reinterpret_cast<const float4*>(&s[up_off]);
        float4 dn4 = *reinterpret_cast<const float4*>(&s[dn_off]);
        float4 lf4 = *reinterpret_cast<const float4*>(&s[e_lf]);
        float4 rt4 = *reinterpret_cast<const float4*>(&s[e_rt]);
        const float upa[4] = {up4.x, up4.y, up4.z, up4.w};
        const float dna[4] = {dn4.x, dn4.y, dn4.z, dn4.w};
        const float lfa[4] = {lf4.x, lf4.y, lf4.z, lf4.w};
        const float rta[4] = {rt4.x, rt4.y, rt4.z, rt4.w};

        float nn[4][4];
#pragma unroll
        for (int i = 0; i < 4; ++i) {
            const float u0 = (i == 0) ? upa[0] : vv[i - 1][0];
            const float u1 = (i == 0) ? upa[1] : vv[i - 1][1];
            const float u2 = (i == 0) ? upa[2] : vv[i - 1][2];
            const float u3 = (i == 0) ? upa[3] : vv[i - 1][3];
            const float d0 = (i == 3) ? dna[0] : vv[i + 1 > 3 ? 3 : i + 1][0];
            const float d1 = (i == 3) ? dna[1] : vv[i + 1 > 3 ? 3 : i + 1][1];
            const float d2 = (i == 3) ? dna[2] : vv[i + 1 > 3 ? 3 : i + 1][2];
            const float d3 = (i == 3) ? dna[3] : vv[i + 1 > 3 ? 3 : i + 1][3];
            nn[i][0] = vv[i][0] - cvv[i][0] * (vv[i][0] - u0) + cvv[i + 1][0] * (d0 - vv[i][0])
                               - hh[i][0] * (vv[i][0] - lfa[i]) + hh[i][1] * (vv[i][1] - vv[i][0]);
            nn[i][1] = vv[i][1] - cvv[i][1] * (vv[i][1] - u1) + cvv[i + 1][1] * (d1 - vv[i][1])
                               - hh[i][1] * (vv[i][1] - vv[i][0]) + hh[i][2] * (vv[i][2] - vv[i][1]);
            nn[i][2] = vv[i][2] - cvv[i][2] * (vv[i][2] - u2) + cvv[i + 1][2] * (d2 - vv[i][2])
                               - hh[i][2] * (vv[i][2] - vv[i][1]) + hh[i][3] * (vv[i][3] - vv[i][2]);
            nn[i][3] = vv[i][3] - cvv[i][3] * (vv[i][3] - u3) + cvv[i + 1][3] * (d3 - vv[i][3])
                               - hh[i][3] * (vv[i][3] - vv[i][2]) + hh[i][4] * (rta[i] - vv[i][3]);
        }

        int nxt = cur ^ 1;
        float* d = sb[nxt];
        *reinterpret_cast<float4*>(&d[w_t])  = float4{nn[0][0], nn[0][1], nn[0][2], nn[0][3]};
        *reinterpret_cast<float4*>(&d[w_b])  = float4{nn[3][0], nn[3][1], nn[3][2], nn[3][3]};
        *reinterpret_cast<float4*>(&d[e_wl]) = float4{nn[0][0], nn[1][0], nn[2][0], nn[3][0]};
        *reinterpret_cast<float4*>(&d[e_wr]) = float4{nn[0][3], nn[1][3], nn[2][3], nn[3][3]};
#pragma unroll
        for (int i = 0; i < 4; ++i) {
            vv[i][0] = nn[i][0]; vv[i][1] = nn[i][1];
            vv[i][2] = nn[i][2]; vv[i][3] = nn[i][3];
        }
        cur = nxt;
        __syncthreads();
    }

    float* dstb = dst + b * IMG;
#pragma unroll
    for (int i = 0; i < 4; ++i) {
        if (isr[i]) {
            float4 o{vv[i][0], vv[i][1], vv[i][2], vv[i][3]};
            if (SUB_SHIFT) { o.x -= shift; o.y -= shift; o.z -= shift; o.w -= shift; }
            *reinterpret_cast<float4*>(dstb + goffr[i]) = o;
        }
    }
}

// -------- fallback (round-2 verified, inline gather, 256 threads) --------
template <bool ADD_SHIFT, bool SUB_SHIFT>
__global__ __launch_bounds__(256, 1) void step_fused(
    const float* __restrict__ src, float* __restrict__ dst,
    const float* __restrict__ cv_g, const float* __restrict__ ch_g,
    const unsigned* __restrict__ key) {
    __shared__ float sb[2][SSZ];
    const int blk = blockIdx.x;
    const int b = blk >> 7, t = blk & 127;
    const int y0 = (t >> 3) * TILE_H, x0 = (t & 7) * TILE_W;
    const float* cvb = cv_g + b * CV_PER_B;
    const float* chb = ch_g + b * CH_PER_B;
    const float* srcb = src + b * IMG;
    float* dstb = dst + b * IMG;
    float shift = 0.f;
    if (ADD_SHIFT || SUB_SHIFT) shift = (kinv(*key) <= DEPS_) ? DEPS_ : 0.f;
    const int tid = threadIdx.x;
    float v[QPT_F][4], cu[QPT_F][4], cd[QPT_F][4], chq[QPT_F][5];
    int roff[QPT_F], rr[QPT_F], xx[QPT_F];
    bool act[QPT_F];
#pragma unroll
    for (int q = 0; q < QPT_F; ++q) {
        int qi = tid + q * 256;
        act[q] = qi < NQUAD;
        int qc = act[q] ? qi : 0;
        int r = qc / NQ_ROW;
        int x = (qc - r * NQ_ROW) * 4;
        rr[q] = r; xx[q] = x;
        roff[q] = (r + 1) * RW + x;
        int gy = y0 - HALO_Y + r, gx = x0 - HALO_X + x;
        bool gy_in = (gy >= 0) && (gy < HH);
#pragma unroll
        for (int j = 0; j < 4; ++j) {
            int gxx = gx + j;
            bool gx_in = (gxx >= 0) && (gxx < WW);
            bool vin = act[q] && gy_in && gx_in;
            float val = vin ? srcb[gy * WW + gxx] : 0.f;
            if (ADD_SHIFT) val += shift;
            v[q][j] = vin ? val : 0.f;
            bool up_ok = act[q] && (r >= 1) && (gy >= 1) && (gy < HH) && gx_in;
            cu[q][j] = up_ok ? LAM * cvb[(gy - 1) * WW + gxx] : 0.f;
            bool dn_ok = act[q] && (r <= RH - 2) && (gy >= 0) && (gy < HH - 1) && gx_in;
            cd[q][j] = dn_ok ? LAM * cvb[gy * WW + gxx] : 0.f;
        }
#pragma unroll
        for (int jj = 0; jj < 5; ++jj) {
            int xe = x + jj, gxe = gx + jj;
            bool ok = act[q] && (xe >= 1) && (xe <= RW - 1) && gy_in &&
                      (gxe >= 1) && (gxe < WW);
            chq[q][jj] = ok ? LAM * chb[gy * (WW - 1) + (gxe - 1)] : 0.f;
        }
    }
    for (int i = tid; i < RW; i += 256) {
        sb[0][i] = 0.f; sb[0][(RH + 1) * RW + i] = 0.f;
        sb[1][i] = 0.f; sb[1][(RH + 1) * RW + i] = 0.f;
    }
#pragma unroll
    for (int q = 0; q < QPT_F; ++q)
        if (act[q])
            *reinterpret_cast<float4*>(&sb[0][roff[q]]) =
                float4{v[q][0], v[q][1], v[q][2], v[q][3]};
    __syncthreads();
    int cur = 0;
    for (int it = 0; it < T_FUSE; ++it) {
        float nv[QPT_F][4];
#pragma unroll
        for (int q = 0; q < QPT_F; ++q) {
            const float* s = sb[cur];
            float4 up = *reinterpret_cast<const float4*>(&s[roff[q] - RW]);
            float4 dn = *reinterpret_cast<const float4*>(&s[roff[q] + RW]);
            float lf = s[roff[q] - 1];
            float rt = s[roff[q] + 4];
            float c0 = v[q][0], c1 = v[q][1], c2 = v[q][2], c3 = v[q][3];
            nv[q][0] = c0 - cu[q][0] * (c0 - up.x) + cd[q][0] * (dn.x - c0)
                          - chq[q][0] * (c0 - lf) + chq[q][1] * (c1 - c0);
            nv[q][1] = c1 - cu[q][1] * (c1 - up.y) + cd[q][1] * (dn.y - c1)
                          - chq[q][1] * (c1 - c0) + chq[q][2] * (c2 - c1);
            nv[q][2] = c2 - cu[q][2] * (c2 - up.z) + cd[q][2] * (dn.z - c2)
                          - chq[q][2] * (c2 - c1) + chq[q][3] * (c3 - c2);
            nv[q][3] = c3 - cu[q][3] * (c3 - up.w) + cd[q][3] * (dn.w - c3)
                          - chq[q][3] * (c3 - c2) + chq[q][4] * (rt - c3);
        }
        int nxt = cur ^ 1;
#pragma unroll
        for (int q = 0; q < QPT_F; ++q) {
            if (act[q])
                *reinterpret_cast<float4*>(&sb[nxt][roff[q]]) =
                    float4{nv[q][0], nv[q][1], nv[q][2], nv[q][3]};
            v[q][0] = nv[q][0]; v[q][1] = nv[q][1];
            v[q][2] = nv[q][2]; v[q][3] = nv[q][3];
        }
        cur = nxt;
        __syncthreads();
    }
#pragma unroll
    for (int q = 0; q < QPT_F; ++q) {
        if (!act[q]) continue;
        int r = rr[q], x = xx[q];
        if (r >= HALO_Y && r < HALO_Y + TILE_H && x >= HALO_X && x < HALO_X + TILE_W) {
            int gy = y0 - HALO_Y + r, gx = x0 - HALO_X + x;
            float4 o{v[q][0], v[q][1], v[q][2], v[q][3]};
            if (SUB_SHIFT) { o.x -= shift; o.y -= shift; o.z -= shift; o.w -= shift; }
            *reinterpret_cast<float4*>(dstb + gy * WW + gx) = o;
        }
    }
}

extern "C" void kernel_launch(void* const* d_in, const int* in_sizes, int n_in,
                              void* d_out, int out_size, void* d_ws, size_t ws_size,
                              hipStream_t stream) {
    const float* guide   = (const float*)d_in[0];
    const float* initial = (const float*)d_in[1];
    float* out    = (float*)d_out;
    float* out_y  = out;
    float* out_cv = out + N_DEPTH;
    float* out_ch = out + N_DEPTH + N_CV;

    unsigned* key = (unsigned*)d_ws;
    float* wsf    = (float*)d_ws;
    float* bufA   = wsf + 64;
    float* bufB   = bufA + N_DEPTH;
    float* blob   = bufB + N_DEPTH;

    const size_t need = (size_t)(64 + 2 * N_DEPTH + 256 * BLOB_BLK) * 4;
    const bool fast = ws_size >= need;

    hipLaunchKernelGGL(init_key_kernel, dim3(1), dim3(1), 0, stream, key);
    hipLaunchKernelGGL(min_kernel, dim3(256), dim3(256), 0, stream, initial, key);

    int nco = N_CV + N_CH;
    hipLaunchKernelGGL(coeff_kernel, dim3((nco + 255) / 256), dim3(256), 0, stream,
                       guide, out_cv, out_ch);
    if (fast)
        hipLaunchKernelGGL(prep_planes, dim3(256), dim3(256), 0, stream,
                           out_cv, out_ch, blob);

    float* bufs[2] = {bufA, bufB};
    for (int k = 0; k < NSS; ++k) {
        const float* src = (k == 0) ? initial : bufs[(k + 1) & 1];
        float*       dst = (k == NSS - 1) ? out_y : bufs[k & 1];
        if (fast) {
            if (k == 0)
                hipLaunchKernelGGL((step_fast<true, false>), dim3(256), dim3(NTF), 0,
                                   stream, src, dst, blob, key);
            else if (k == NSS - 1)
                hipLaunchKernelGGL((step_fast<false, true>), dim3(256), dim3(NTF), 0,
                                   stream, src, dst, blob, key);
            else
                hipLaunchKernelGGL((step_fast<false, false>), dim3(256), dim3(NTF), 0,
                                   stream, src, dst, blob, key);
        } else {
            if (k == 0)
                hipLaunchKernelGGL((step_fused<true, false>), dim3(256), dim3(256), 0,
                                   stream, src, dst, out_cv, out_ch, key);
            else if (k == NSS - 1)
                hipLaunchKernelGGL((step_fused<false, true>), dim3(256), dim3(256), 0,
                                   stream, src, dst, out_cv, out_ch, key);
            else
                hipLaunchKernelGGL((step_fused<false, false>), dim3(256), dim3(256), 0,
                                   stream, src, dst, out_cv, out_ch, key);
        }
    }
}

// Round 5
// 568.384 us; speedup vs baseline: 1.0052x; 1.0052x over previous
//
#include <hip/hip_runtime.h>

// Perona-Malik diffusion, 500 iters = 50 launches x 10 LDS-fused steps.
// Round-9: round-8's 4x4/5-wave rewrite REVERTED (fewer waves removed all
// latency hiding in the barrier-lockstep loop: 495->571). Back to the
// verified 4x2-unit structure (round 7, 495 us), now with TWO blocks per CU:
// 512 blocks, tile 32x32 (region 56x52), 364 units, 384 threads = 6 waves,
// 40 KB LDS/block. Two independent barrier domains per CU overlap each
// other's ds_read-latency + waitcnt + barrier stalls (the measured ~40% of
// iter time that DS/conflict fixes couldn't touch). Per-cell coefficients
// and neighbor values are identical -> bit-identical output. Fallback path
// unchanged on its own 256-block geometry.

#define HH 512
#define WW 512
#define NB 2
static constexpr float LAM   = 0.24f;
static constexpr float KCOND = 0.03f;
static constexpr float DEPS_ = 0.1f;
static constexpr int IMG      = HH * WW;
static constexpr int N_DEPTH  = NB * IMG;
static constexpr int CV_PER_B = (HH - 1) * WW;
static constexpr int CH_PER_B = HH * (WW - 1);
static constexpr int N_CV     = NB * CV_PER_B;
static constexpr int N_CH     = NB * CH_PER_B;

static constexpr int T_FUSE = 10, NSS = 50;       // 50 x 10 = 500
static constexpr int HALO_X = 12, HALO_Y = 10;

// ---- fallback geometry (round-2 verified, untouched): tile 64x32 ----
static constexpr int TILE_W = 64, TILE_H = 32;
static constexpr int RW = TILE_W + 2 * HALO_X;    // 88
static constexpr int RH = TILE_H + 2 * HALO_Y;    // 52
static constexpr int NQ_ROW = RW / 4;             // 22
static constexpr int NQUAD  = NQ_ROW * RH;        // 1144
static constexpr int SSZ    = (RH + 2) * RW;      // 4752
static constexpr int QPT_F = 5;

// ---- fast path: tile 32x32, 4x2 units, 2 blocks/CU ----
static constexpr int FTW = 32, FTH = 32;
static constexpr int FRW = FTW + 2 * HALO_X;       // 56
static constexpr int FRH = FTH + 2 * HALO_Y;       // 52
static constexpr int F_NU_ROW = FRW / 4;           // 14 units per row-pair
static constexpr int F_NU_COL = FRH / 2;           // 26 row-pairs
static constexpr int F_NUNIT  = F_NU_ROW * F_NU_COL; // 364
static constexpr int F_NT     = 384;               // 6 waves
static constexpr int F_NBLK   = NB * 256;          // 512 blocks (16x16 tiles)

// fast-path LDS layout (floats), per ping-pong buffer:
//   rows : (FRH+2) x FS (stride 60), trash: 20 lanes x 16, edge: per-unit
//   float4 {v0[0],v1[0],v0[3],v1[3]} (+1 shifted, sentinel entries 0)
static constexpr int FS        = 60;
static constexpr int F_ROWS    = (FRH + 2) * FS;         // 3240
static constexpr int F_TRASH   = F_ROWS;                 // 3240
static constexpr int F_TRASH_SZ = (F_NT - F_NUNIT) * 16; // 320
static constexpr int F_EDGE    = F_TRASH + F_TRASH_SZ;   // 3560 (16B aligned)
static constexpr int F_ECNT    = F_NUNIT + 2;            // 366
static constexpr int F_BUF     = F_EDGE + F_ECNT * 4;    // 5024 (40.2KB x2)

// fast coefficient planes (per block)
static constexpr int F_CVW   = FRW;                      // 56
static constexpr int F_CV_SZ = (FRH + 1) * F_CVW;        // 2968
static constexpr int F_CHW   = FRW + 8;                  // 64
static constexpr int F_CH_SZ = FRH * F_CHW;              // 3328
static constexpr int F_BLOB  = F_CV_SZ + F_CH_SZ;        // 6296 floats/block

// ---- monotone float<->uint key for atomic min ----
__device__ __forceinline__ unsigned fkey(float f) {
    unsigned u = __float_as_uint(f);
    return (u & 0x80000000u) ? ~u : (u | 0x80000000u);
}
__device__ __forceinline__ float kinv(unsigned k) {
    return __uint_as_float((k & 0x80000000u) ? (k & 0x7fffffffu) : ~k);
}

__global__ void init_key_kernel(unsigned* key) { *key = 0xFFFFFFFFu; }

__global__ void min_kernel(const float* __restrict__ x, unsigned* key) {
    float m = 3.4e38f;
    for (int idx = blockIdx.x * blockDim.x + threadIdx.x; idx < N_DEPTH;
         idx += gridDim.x * blockDim.x)
        m = fminf(m, x[idx]);
    for (int off = 32; off > 0; off >>= 1) m = fminf(m, __shfl_down(m, off, 64));
    __shared__ float sm[4];
    int lane = threadIdx.x & 63, wv = threadIdx.x >> 6;
    if (lane == 0) sm[wv] = m;
    __syncthreads();
    if (threadIdx.x == 0) {
        float mm = fminf(fminf(sm[0], sm[1]), fminf(sm[2], sm[3]));
        atomicMin(key, fkey(mm));
    }
}

__global__ void coeff_kernel(const float* __restrict__ g, float* __restrict__ cv,
                             float* __restrict__ chh) {
    int idx = blockIdx.x * blockDim.x + threadIdx.x;
    constexpr float kk = KCOND * KCOND;
    if (idx < N_CV) {
        int b = idx / CV_PER_B;
        int r = idx - b * CV_PER_B;
        int i = r >> 9, j = r & (WW - 1);
        const float* gb = g + b * 3 * IMG + i * WW + j;
        float s = 0.f;
#pragma unroll
        for (int c = 0; c < 3; ++c) s += fabsf(gb[c * IMG + WW] - gb[c * IMG]);
        float m = s / 3.0f;
        cv[idx] = 1.0f / (1.0f + (m * m) / kk);
    } else if (idx < N_CV + N_CH) {
        int t = idx - N_CV;
        int b = t / CH_PER_B;
        int r = t - b * CH_PER_B;
        int i = r / (WW - 1);
        int j = r - i * (WW - 1);
        const float* gb = g + b * 3 * IMG + i * WW + j;
        float s = 0.f;
#pragma unroll
        for (int c = 0; c < 3; ++c) s += fabsf(gb[c * IMG + 1] - gb[c * IMG]);
        float m = s / 3.0f;
        chh[t] = 1.0f / (1.0f + (m * m) / kk);
    }
}

// One-time: bake predicated L*cv / L*ch into dense per-block planes
// (fast-path 512-block geometry).
// CV[rr][x] = coeff of vertical edge ABOVE region row rr (0 where invalid).
// CH[rr][xe] = coeff of horizontal edge whose RIGHT pixel is region col xe.
__global__ __launch_bounds__(256) void prep_planes(const float* __restrict__ cv_g,
                                                   const float* __restrict__ ch_g,
                                                   float* __restrict__ blob) {
    const int blk = blockIdx.x;
    const int b   = blk >> 8, t = blk & 255;
    const int y0  = (t >> 4) * FTH;
    const int x0  = (t & 15) * FTW;
    const float* cvb = cv_g + b * CV_PER_B;
    const float* chb = ch_g + b * CH_PER_B;
    float* pv = blob + blk * F_BLOB;
    float* ph = pv + F_CV_SZ;
    for (int i = threadIdx.x; i < F_CV_SZ; i += 256) {
        int rr = i / F_CVW, x = i - rr * F_CVW;
        int gy = y0 - HALO_Y + rr, gx = x0 - HALO_X + x;
        bool ok = (rr >= 1) && (rr <= FRH - 1) && (gy >= 1) && (gy <= HH - 1) &&
                  (gx >= 0) && (gx < WW);
        pv[i] = ok ? LAM * cvb[(gy - 1) * WW + gx] : 0.f;
    }
    for (int i = threadIdx.x; i < F_CH_SZ; i += 256) {
        int rr = i / F_CHW, xe = i - rr * F_CHW;
        int gy = y0 - HALO_Y + rr, gxe = x0 - HALO_X + xe;
        bool ok = (xe >= 1) && (xe <= FRW - 1) && (gy >= 0) && (gy < HH) &&
                  (gxe >= 1) && (gxe < WW);
        ph[i] = ok ? LAM * chb[gy * (WW - 1) + (gxe - 1)] : 0.f;
    }
}

template <bool ADD_SHIFT, bool SUB_SHIFT>
__global__ __launch_bounds__(F_NT, 3) void step_fast(
    const float* __restrict__ src, float* __restrict__ dst,
    const float* __restrict__ blob, const unsigned* __restrict__ key) {
    __shared__ float sb[2][F_BUF];
    const int blk = blockIdx.x;
    const int b   = blk >> 8, t = blk & 255;
    const int y0  = (t >> 4) * FTH;
    const int x0  = (t & 15) * FTW;
    const float* srcb = src + b * IMG;
    const float* pv   = blob + blk * F_BLOB;
    const float* ph   = pv + F_CV_SZ;

    float shift = 0.f;
    if (ADD_SHIFT || SUB_SHIFT) shift = (kinv(*key) <= DEPS_) ? DEPS_ : 0.f;
    const int tid = threadIdx.x;

    // ---- unit geometry: 4 wide x 2 tall, rows r0=2*pr, r1=r0+1 ----
    const bool act = tid < F_NUNIT;
    const int  uc  = act ? tid : 0;
    const int  pr  = uc / F_NU_ROW;
    const int  px  = uc - pr * F_NU_ROW;
    const int  x   = px * 4;
    const int  r0  = 2 * pr, r1 = r0 + 1;
    int roff0 = (r0 + 1) * FS + x;
    int roff1 = roff0 + FS;
    int e_w   = F_EDGE + (tid + 1) * 4;           // own edge write
    if (!act) {                                   // distinct trash slots
        int ts = F_TRASH + (tid - F_NUNIT) * 16;
        roff0 = ts; roff1 = ts + 4; e_w = ts + 8;
    }
    const int e_lf = F_EDGE + uc * 4 + 2;         // left nbr's {v0[3],v1[3]}
    const int e_rt = F_EDGE + (uc + 2) * 4;       // right nbr's {v0[0],v1[0]}

    const int gy0 = y0 - HALO_Y + r0, gy1 = gy0 + 1;
    const int gx  = x0 - HALO_X + x;
    const bool gx_in = (gx >= 0) && (gx <= WW - 4);
    const bool in0 = act && gx_in && (gy0 >= 0) && (gy0 < HH);
    const bool in1 = act && gx_in && (gy1 >= 0) && (gy1 < HH);
    const int goff0 = in0 ? (gy0 * WW + gx) : 0;
    const int goff1 = in1 ? (gy1 * WW + gx) : 0;
    const bool is_int = act && (r0 >= HALO_Y) && (r1 < HALO_Y + FTH) &&
                        (x >= HALO_X) && (x < HALO_X + FTW);

    // ---- coefficients (baked, predicated; zero-mask inactive lanes) ----
    const float am = act ? 1.f : 0.f;
    float ca[4], cm[4], cb[4], h0[5], h1[5];
    {
        float4 a = *reinterpret_cast<const float4*>(&pv[r0 * F_CVW + x]);        // above r0
        float4 m = *reinterpret_cast<const float4*>(&pv[r1 * F_CVW + x]);        // r0-r1
        float4 d = *reinterpret_cast<const float4*>(&pv[(r1 + 1) * F_CVW + x]);  // below r1
        ca[0] = a.x * am; ca[1] = a.y * am; ca[2] = a.z * am; ca[3] = a.w * am;
        cm[0] = m.x * am; cm[1] = m.y * am; cm[2] = m.z * am; cm[3] = m.w * am;
        cb[0] = d.x * am; cb[1] = d.y * am; cb[2] = d.z * am; cb[3] = d.w * am;
        float4 u = *reinterpret_cast<const float4*>(&ph[r0 * F_CHW + x]);
        float  u4 = ph[r0 * F_CHW + x + 4];
        float4 w = *reinterpret_cast<const float4*>(&ph[r1 * F_CHW + x]);
        float  w4 = ph[r1 * F_CHW + x + 4];
        h0[0] = u.x * am; h0[1] = u.y * am; h0[2] = u.z * am; h0[3] = u.w * am; h0[4] = u4 * am;
        h1[0] = w.x * am; h1[1] = w.y * am; h1[2] = w.z * am; h1[3] = w.w * am; h1[4] = w4 * am;
    }

    // ---- initial state ----
    float v0[4] = {0.f, 0.f, 0.f, 0.f}, v1[4] = {0.f, 0.f, 0.f, 0.f};
    if (in0) {
        float4 tv = *reinterpret_cast<const float4*>(srcb + goff0);
        if (ADD_SHIFT) { tv.x += shift; tv.y += shift; tv.z += shift; tv.w += shift; }
        v0[0] = tv.x; v0[1] = tv.y; v0[2] = tv.z; v0[3] = tv.w;
    }
    if (in1) {
        float4 tv = *reinterpret_cast<const float4*>(srcb + goff1);
        if (ADD_SHIFT) { tv.x += shift; tv.y += shift; tv.z += shift; tv.w += shift; }
        v1[0] = tv.x; v1[1] = tv.y; v1[2] = tv.z; v1[3] = tv.w;
    }

    // guard rows (rows 0 and FRH+1) zeroed in both buffers
    for (int i = tid; i < FS; i += F_NT) {
        sb[0][i] = 0.f; sb[0][(FRH + 1) * FS + i] = 0.f;
        sb[1][i] = 0.f; sb[1][(FRH + 1) * FS + i] = 0.f;
    }
    if (tid == 0) {
        float4 z{0.f, 0.f, 0.f, 0.f};
        *reinterpret_cast<float4*>(&sb[0][F_EDGE]) = z;                      // entry 0
        *reinterpret_cast<float4*>(&sb[1][F_EDGE]) = z;
        *reinterpret_cast<float4*>(&sb[0][F_EDGE + (F_ECNT - 1) * 4]) = z;   // sentinel
        *reinterpret_cast<float4*>(&sb[1][F_EDGE + (F_ECNT - 1) * 4]) = z;
    }
    *reinterpret_cast<float4*>(&sb[0][roff0]) = float4{v0[0], v0[1], v0[2], v0[3]};
    *reinterpret_cast<float4*>(&sb[0][roff1]) = float4{v1[0], v1[1], v1[2], v1[3]};
    *reinterpret_cast<float4*>(&sb[0][e_w])   = float4{v0[0], v1[0], v0[3], v1[3]};
    __syncthreads();

    int cur = 0;
    for (int it = 0; it < T_FUSE; ++it) {
        const float* s = sb[cur];
        float2 lfp = *reinterpret_cast<const float2*>(&s[e_lf]);  // {lf0, lf1}
        float2 rtp = *reinterpret_cast<const float2*>(&s[e_rt]);  // {rt0, rt1}
        float4 up = *reinterpret_cast<const float4*>(&s[roff0 - FS]);
        float4 dn = *reinterpret_cast<const float4*>(&s[roff1 + FS]);

        float n0[4], n1[4];
        // top row: up from LDS, down-neighbor = v1 (registers)
        n0[0] = v0[0] - ca[0] * (v0[0] - up.x) + cm[0] * (v1[0] - v0[0])
                      - h0[0] * (v0[0] - lfp.x) + h0[1] * (v0[1] - v0[0]);
        n0[1] = v0[1] - ca[1] * (v0[1] - up.y) + cm[1] * (v1[1] - v0[1])
                      - h0[1] * (v0[1] - v0[0]) + h0[2] * (v0[2] - v0[1]);
        n0[2] = v0[2] - ca[2] * (v0[2] - up.z) + cm[2] * (v1[2] - v0[2])
                      - h0[2] * (v0[2] - v0[1]) + h0[3] * (v0[3] - v0[2]);
        n0[3] = v0[3] - ca[3] * (v0[3] - up.w) + cm[3] * (v1[3] - v0[3])
                      - h0[3] * (v0[3] - v0[2]) + h0[4] * (rtp.x - v0[3]);
        // bottom row: up-neighbor = v0 (registers), down from LDS
        n1[0] = v1[0] - cm[0] * (v1[0] - v0[0]) + cb[0] * (dn.x - v1[0])
                      - h1[0] * (v1[0] - lfp.y) + h1[1] * (v1[1] - v1[0]);
        n1[1] = v1[1] - cm[1] * (v1[1] - v0[1]) + cb[1] * (dn.y - v1[1])
                      - h1[1] * (v1[1] - v1[0]) + h1[2] * (v1[2] - v1[1]);
        n1[2] = v1[2] - cm[2] * (v1[2] - v0[2]) + cb[2] * (dn.z - v1[2])
                      - h1[2] * (v1[2] - v1[1]) + h1[3] * (v1[3] - v1[2]);
        n1[3] = v1[3] - cm[3] * (v1[3] - v0[3]) + cb[3] * (dn.w - v1[3])
                      - h1[3] * (v1[3] - v1[2]) + h1[4] * (rtp.y - v1[3]);

        int nxt = cur ^ 1;
        float* d = sb[nxt];
        *reinterpret_cast<float4*>(&d[roff0]) = float4{n0[0], n0[1], n0[2], n0[3]};
        *reinterpret_cast<float4*>(&d[roff1]) = float4{n1[0], n1[1], n1[2], n1[3]};
        *reinterpret_cast<float4*>(&d[e_w])   = float4{n0[0], n1[0], n0[3], n1[3]};
        v0[0] = n0[0]; v0[1] = n0[1]; v0[2] = n0[2]; v0[3] = n0[3];
        v1[0] = n1[0]; v1[1] = n1[1]; v1[2] = n1[2]; v1[3] = n1[3];
        cur = nxt;
        __syncthreads();
    }

    float* dstb = dst + b * IMG;
    if (is_int) {
        float4 o0{v0[0], v0[1], v0[2], v0[3]};
        float4 o1{v1[0], v1[1], v1[2], v1[3]};
        if (SUB_SHIFT) {
            o0.x -= shift; o0.y -= shift; o0.z -= shift; o0.w -= shift;
            o1.x -= shift; o1.y -= shift; o1.z -= shift; o1.w -= shift;
        }
        *reinterpret_cast<float4*>(dstb + goff0) = o0;
        *reinterpret_cast<float4*>(dstb + goff1) = o1;
    }
}

// -------- fallback (round-2 verified, inline gather, 256 threads) --------
template <bool ADD_SHIFT, bool SUB_SHIFT>
__global__ __launch_bounds__(256, 1) void step_fused(
    const float* __restrict__ src, float* __restrict__ dst,
    const float* __restrict__ cv_g, const float* __restrict__ ch_g,
    const unsigned* __restrict__ key) {
    __shared__ float sb[2][SSZ];
    const int blk = blockIdx.x;
    const int b = blk >> 7, t = blk & 127;
    const int y0 = (t >> 3) * TILE_H, x0 = (t & 7) * TILE_W;
    const float* cvb = cv_g + b * CV_PER_B;
    const float* chb = ch_g + b * CH_PER_B;
    const float* srcb = src + b * IMG;
    float* dstb = dst + b * IMG;
    float shift = 0.f;
    if (ADD_SHIFT || SUB_SHIFT) shift = (kinv(*key) <= DEPS_) ? DEPS_ : 0.f;
    const int tid = threadIdx.x;
    float v[QPT_F][4], cu[QPT_F][4], cd[QPT_F][4], chq[QPT_F][5];
    int roff[QPT_F], rr[QPT_F], xx[QPT_F];
    bool act[QPT_F];
#pragma unroll
    for (int q = 0; q < QPT_F; ++q) {
        int qi = tid + q * 256;
        act[q] = qi < NQUAD;
        int qc = act[q] ? qi : 0;
        int r = qc / NQ_ROW;
        int x = (qc - r * NQ_ROW) * 4;
        rr[q] = r; xx[q] = x;
        roff[q] = (r + 1) * RW + x;
        int gy = y0 - HALO_Y + r, gx = x0 - HALO_X + x;
        bool gy_in = (gy >= 0) && (gy < HH);
#pragma unroll
        for (int j = 0; j < 4; ++j) {
            int gxx = gx + j;
            bool gx_in = (gxx >= 0) && (gxx < WW);
            bool vin = act[q] && gy_in && gx_in;
            float val = vin ? srcb[gy * WW + gxx] : 0.f;
            if (ADD_SHIFT) val += shift;
            v[q][j] = vin ? val : 0.f;
            bool up_ok = act[q] && (r >= 1) && (gy >= 1) && (gy < HH) && gx_in;
            cu[q][j] = up_ok ? LAM * cvb[(gy - 1) * WW + gxx] : 0.f;
            bool dn_ok = act[q] && (r <= RH - 2) && (gy >= 0) && (gy < HH - 1) && gx_in;
            cd[q][j] = dn_ok ? LAM * cvb[gy * WW + gxx] : 0.f;
        }
#pragma unroll
        for (int jj = 0; jj < 5; ++jj) {
            int xe = x + jj, gxe = gx + jj;
            bool ok = act[q] && (xe >= 1) && (xe <= RW - 1) && gy_in &&
                      (gxe >= 1) && (gxe < WW);
            chq[q][jj] = ok ? LAM * chb[gy * (WW - 1) + (gxe - 1)] : 0.f;
        }
    }
    for (int i = tid; i < RW; i += 256) {
        sb[0][i] = 0.f; sb[0][(RH + 1) * RW + i] = 0.f;
        sb[1][i] = 0.f; sb[1][(RH + 1) * RW + i] = 0.f;
    }
#pragma unroll
    for (int q = 0; q < QPT_F; ++q)
        if (act[q])
            *reinterpret_cast<float4*>(&sb[0][roff[q]]) =
                float4{v[q][0], v[q][1], v[q][2], v[q][3]};
    __syncthreads();
    int cur = 0;
    for (int it = 0; it < T_FUSE; ++it) {
        float nv[QPT_F][4];
#pragma unroll
        for (int q = 0; q < QPT_F; ++q) {
            const float* s = sb[cur];
            float4 up = *reinterpret_cast<const float4*>(&s[roff[q] - RW]);
            float4 dn = *reinterpret_cast<const float4*>(&s[roff[q] + RW]);
            float lf = s[roff[q] - 1];
            float rt = s[roff[q] + 4];
            float c0 = v[q][0], c1 = v[q][1], c2 = v[q][2], c3 = v[q][3];
            nv[q][0] = c0 - cu[q][0] * (c0 - up.x) + cd[q][0] * (dn.x - c0)
                          - chq[q][0] * (c0 - lf) + chq[q][1] * (c1 - c0);
            nv[q][1] = c1 - cu[q][1] * (c1 - up.y) + cd[q][1] * (dn.y - c1)
                          - chq[q][1] * (c1 - c0) + chq[q][2] * (c2 - c1);
            nv[q][2] = c2 - cu[q][2] * (c2 - up.z) + cd[q][2] * (dn.z - c2)
                          - chq[q][2] * (c2 - c1) + chq[q][3] * (c3 - c2);
            nv[q][3] = c3 - cu[q][3] * (c3 - up.w) + cd[q][3] * (dn.w - c3)
                          - chq[q][3] * (c3 - c2) + chq[q][4] * (rt - c3);
        }
        int nxt = cur ^ 1;
#pragma unroll
        for (int q = 0; q < QPT_F; ++q) {
            if (act[q])
                *reinterpret_cast<float4*>(&sb[nxt][roff[q]]) =
                    float4{nv[q][0], nv[q][1], nv[q][2], nv[q][3]};
            v[q][0] = nv[q][0]; v[q][1] = nv[q][1];
            v[q][2] = nv[q][2]; v[q][3] = nv[q][3];
        }
        cur = nxt;
        __syncthreads();
    }
#pragma unroll
    for (int q = 0; q < QPT_F; ++q) {
        if (!act[q]) continue;
        int r = rr[q], x = xx[q];
        if (r >= HALO_Y && r < HALO_Y + TILE_H && x >= HALO_X && x < HALO_X + TILE_W) {
            int gy = y0 - HALO_Y + r, gx = x0 - HALO_X + x;
            float4 o{v[q][0], v[q][1], v[q][2], v[q][3]};
            if (SUB_SHIFT) { o.x -= shift; o.y -= shift; o.z -= shift; o.w -= shift; }
            *reinterpret_cast<float4*>(dstb + gy * WW + gx) = o;
        }
    }
}

extern "C" void kernel_launch(void* const* d_in, const int* in_sizes, int n_in,
                              void* d_out, int out_size, void* d_ws, size_t ws_size,
                              hipStream_t stream) {
    const float* guide   = (const float*)d_in[0];
    const float* initial = (const float*)d_in[1];
    float* out    = (float*)d_out;
    float* out_y  = out;
    float* out_cv = out + N_DEPTH;
    float* out_ch = out + N_DEPTH + N_CV;

    unsigned* key = (unsigned*)d_ws;
    float* wsf    = (float*)d_ws;
    float* bufA   = wsf + 64;
    float* bufB   = bufA + N_DEPTH;
    float* blob   = bufB + N_DEPTH;

    const size_t need = (size_t)(64 + 2 * N_DEPTH + (size_t)F_NBLK * F_BLOB) * 4;
    const bool fast = ws_size >= need;

    hipLaunchKernelGGL(init_key_kernel, dim3(1), dim3(1), 0, stream, key);
    hipLaunchKernelGGL(min_kernel, dim3(256), dim3(256), 0, stream, initial, key);

    int nco = N_CV + N_CH;
    hipLaunchKernelGGL(coeff_kernel, dim3((nco + 255) / 256), dim3(256), 0, stream,
                       guide, out_cv, out_ch);
    if (fast)
        hipLaunchKernelGGL(prep_planes, dim3(F_NBLK), dim3(256), 0, stream,
                           out_cv, out_ch, blob);

    float* bufs[2] = {bufA, bufB};
    for (int k = 0; k < NSS; ++k) {
        const float* src = (k == 0) ? initial : bufs[(k + 1) & 1];
        float*       dst = (k == NSS - 1) ? out_y : bufs[k & 1];
        if (fast) {
            if (k == 0)
                hipLaunchKernelGGL((step_fast<true, false>), dim3(F_NBLK), dim3(F_NT), 0,
                                   stream, src, dst, blob, key);
            else if (k == NSS - 1)
                hipLaunchKernelGGL((step_fast<false, true>), dim3(F_NBLK), dim3(F_NT), 0,
                                   stream, src, dst, blob, key);
            else
                hipLaunchKernelGGL((step_fast<false, false>), dim3(F_NBLK), dim3(F_NT), 0,
                                   stream, src, dst, blob, key);
        } else {
            if (k == 0)
                hipLaunchKernelGGL((step_fused<true, false>), dim3(256), dim3(256), 0,
                                   stream, src, dst, out_cv, out_ch, key);
            else if (k == NSS - 1)
                hipLaunchKernelGGL((step_fused<false, true>), dim3(256), dim3(256), 0,
                                   stream, src, dst, out_cv, out_ch, key);
            else
                hipLaunchKernelGGL((step_fused<false, false>), dim3(256), dim3(256), 0,
                                   stream, src, dst, out_cv, out_ch, key);
        }
    }
}